// Round 1
// 134.356 us; speedup vs baseline: 1.1488x; 1.1488x over previous
//
#include <hip/hip_runtime.h>
#include <hip/hip_bf16.h>

#define NATC 10000
#define NATP 10016          // padded atom count for MFMA m-tiles
#define NNC 32
#define RSNC 16
#define THETANC 8
#define NEMBC 4
#define FEATC 576

typedef __attribute__((ext_vector_type(8))) short short8;  // 8 bf16 (4 VGPRs)
typedef __attribute__((ext_vector_type(4))) float f32x4;
typedef __attribute__((ext_vector_type(2))) float f32x2;

static __device__ __forceinline__ short f2bf(float x) {
    union { __hip_bfloat16 h; short s; } u;
    u.h = __float2bfloat16(x);
    return u.s;
}

// ---------------------------------------------------------------------------
// Kernel 0: pack W1 (576x64) and W2 (64x64) into bf16 MFMA B-fragment order.
// Also initializes out[0] = NATC*b3 (replaces the hipMemsetAsync node).
// ---------------------------------------------------------------------------
__global__ __launch_bounds__(256) void prep_kernel(
    const float* __restrict__ W1, const float* __restrict__ W2,
    const float* __restrict__ b3,
    ushort* __restrict__ W1p, ushort* __restrict__ W2p,
    float* __restrict__ out)
{
    const int gid = blockIdx.x * 256 + threadIdx.x;   // 0..5119
    if (gid == 0) out[0] = (float)NATC * b3[0];
    if (gid < 4608) {                                 // W1: 18 ks * 4 nt * 64 l
        const int l = gid & 63, ntks = gid >> 6;
        const int nt = ntks & 3, ks = ntks >> 2;
        const int q = l >> 4, c = l & 15;
        ushort pk[8];
        #pragma unroll
        for (int jj = 0; jj < 8; ++jj)
            pk[jj] = (ushort)f2bf(W1[(ks * 32 + q * 8 + jj) * 64 + nt * 16 + c]);
        #pragma unroll
        for (int jj = 0; jj < 8; ++jj) W1p[gid * 8 + jj] = pk[jj];
    } else {                                          // W2: 2 ks * 4 nt * 64 l
        const int g = gid - 4608;
        const int l = g & 63, ntks = g >> 6;
        const int nt = ntks & 3, ks = ntks >> 2;
        const int q = l >> 4, c = l & 15;
        ushort pk[8];
        #pragma unroll
        for (int jj = 0; jj < 8; ++jj)
            pk[jj] = (ushort)f2bf(W2[(ks * 32 + q * 8 + jj) * 64 + nt * 16 + c]);
        #pragma unroll
        for (int jj = 0; jj < 8; ++jj) W2p[g * 8 + jj] = pk[jj];
    }
}

// ---------------------------------------------------------------------------
// Kernel 1: per-atom descriptor via MFMA. One block (256 thr) per atom.
//  - cos/sin matrix stored INTERLEAVED (c,s) pairs, row stride 68 f32:
//    A-frag operands load as 4x ds_read_b128 per mt (bank-uniform).
//  - P stored TRANSPOSED (Pt[p][k], stride 36 f32): epilogue/pack/radial all
//    read contiguous k -> ds_read_b128, bank-uniform.
//  - theta trig (S*cos, S*sin with S = 2^(-15/16), S^16 = 2^-15) precomputed
//    once in LDS; prefactor folded into the pow-16 chain.
//  - Pb (bf16 B-frags) aliases the dead geo/bessel/species region.
// LDS = 9216 (Pt) + 8704 (cs) + 64 (thc) + 4096 (union) = 22080 B -> 7 blk/CU.
// ---------------------------------------------------------------------------
__global__ __launch_bounds__(256, 7) void desc_kernel(
    const float* __restrict__ pos,
    const float* __restrict__ spe,
    const float* __restrict__ theta_s,
    const float* __restrict__ kn_rad,
    const int* __restrict__ nidx,
    ushort* __restrict__ descb)
{
    constexpr float RC = 5.0f;
    constexpr float PI_F = 3.14159265358979323846f;
    constexpr float SF = 0.52213689121f;   // 2^(-15/16); SF^16 = 2^(1-16)

    __shared__ f32x4 Pt4[64 * 9];          // P^T: Pt[p*36 + k], pad to 36
    __shared__ f32x4 cs4[32 * 17];         // row kk: [c(j0),s(j0),c(j1),s(j1),...], stride 68
    __shared__ float thc[16];              // {S*cos(th_t), S*sin(th_t)} x 8
    __shared__ __attribute__((aligned(16))) char uni[4096];

    float* const Pt    = (float*)Pt4;
    float* const ux    = (float*)uni;      // 32
    float* const uy    = ux + 32;
    float* const uz    = ux + 64;
    float* const rbase = ux + 96;
    float* const rw    = ux + 128;
    float* const bfs   = ux + 160;         // 32*17 floats, ends at float 704
    float* const ses   = ux + 704;         // 32*5 floats,  ends at float 864
    short* const Pb    = (short*)uni;      // 4096 B, valid from phase 3 on

    const int i   = blockIdx.x;
    const int tid = threadIdx.x;

    // --- phase 0: bond geometry (wave 0) + theta trig table (wave 1) ---
    if (tid < NNC) {
        const int j = tid;
        const int n = nidx[i * NNC + j];
        const float pix = pos[i * 3 + 0], piy = pos[i * 3 + 1], piz = pos[i * 3 + 2];
        const float dx = pos[n * 3 + 0] - pix;
        const float dy = pos[n * 3 + 1] - piy;
        const float dz = pos[n * 3 + 2] - piz;
        const float r = sqrtf(dx * dx + dy * dy + dz * dz) + 1e-8f;
        const float inv = 1.0f / r;
        ux[j] = dx * inv; uy[j] = dy * inv; uz[j] = dz * inv;
        const float fc = (r < RC) ? 0.5f * (cosf(PI_F * r * (1.0f / RC)) + 1.0f) : 0.0f;
        rbase[j] = sqrtf(2.0f / RC) * inv * fc;
        rw[j]    = (PI_F / RC) * kn_rad[0] * r;
        #pragma unroll
        for (int m = 0; m < NEMBC; ++m)
            ses[j * 5 + m] = spe[n * NEMBC + m] * spe[i * NEMBC + m];
    } else if (tid >= 64 && tid < 72) {
        const int t = tid - 64;
        const float th = theta_s[t];
        thc[2 * t]     = SF * cosf(th);
        thc[2 * t + 1] = SF * sinf(th);
    }
    __syncthreads();

    // --- phase 1: bessel basis (512 items) ---
    #pragma unroll
    for (int k = 0; k < 2; ++k) {
        const int e = tid + k * 256;
        const int j = e >> 4, l = e & 15;
        bfs[j * 17 + l] = rbase[j] * sinf(rw[j] * (float)(l + 1));
    }
    __syncthreads();

    // --- phase 2: P^T (stride 36) + interleaved cos/sin matrix (stride 68) ---
    #pragma unroll
    for (int k = 0; k < 8; ++k) {
        const int e = tid + k * 256;
        const int j = e & 31, p = e >> 5;          // j per-lane -> 2-way writes (free)
        Pt[p * 36 + j] = bfs[j * 17 + (p >> 2)] * ses[j * 5 + (p & 3)];
    }
    #pragma unroll
    for (int k = 0; k < 4; ++k) {
        const int e = tid + k * 256;
        const int kk = e & 31, j = e >> 5;
        float cv = ux[j] * ux[kk] + uy[j] * uy[kk] + uz[j] * uz[kk];
        cv = fminf(fmaxf(cv, -1.0f + 1e-6f), 1.0f - 1e-6f);
        f32x2 csv;
        csv[0] = cv;
        csv[1] = sqrtf(fmaxf(1.0f - cv * cv, 0.0f));
        ((f32x2*)cs4)[kk * 34 + j] = csv;          // 8B store, bank-uniform
    }
    __syncthreads();

    // --- phase 3: pack Pb (bf16 B-frags, b128 loads) + radial descriptor ---
    {
        const int nt = tid >> 6, l2 = tid & 63;
        const int q2 = l2 >> 4, c2 = l2 & 15;
        const f32x4 x0 = Pt4[(nt * 16 + c2) * 9 + q2 * 2];
        const f32x4 x1 = Pt4[(nt * 16 + c2) * 9 + q2 * 2 + 1];
        short8 pk;
        pk[0] = f2bf(x0[0]); pk[1] = f2bf(x0[1]); pk[2] = f2bf(x0[2]); pk[3] = f2bf(x0[3]);
        pk[4] = f2bf(x1[0]); pk[5] = f2bf(x1[1]); pk[6] = f2bf(x1[2]); pk[7] = f2bf(x1[3]);
        *(short8*)&Pb[tid * 8] = pk;               // (nt*64+l2) == tid
    }
    if (tid < 64) {
        const f32x4* pr = &Pt4[tid * 9];
        float s = 0.0f;
        #pragma unroll
        for (int kb = 0; kb < 8; ++kb) {
            const f32x4 v = pr[kb];
            s += v[0]; s += v[1]; s += v[2]; s += v[3];   // same j-ascending order
        }
        descb[(size_t)i * FEATC + tid] = (ushort)f2bf(s);
    }
    __syncthreads();

    // --- phase 4: MFMA contraction per theta ---
    const int w = tid >> 6, l = tid & 63;
    const int q = l >> 4, c = l & 15;

    #pragma unroll
    for (int tt = 0; tt < 2; ++tt) {
        const int t = w + tt * 4;
        const float tc = thc[2 * t], ts = thc[2 * t + 1];

        // A-fragments from interleaved (c,s): 4x ds_read_b128 per mt.
        short8 afr[2];
        #pragma unroll
        for (int mt = 0; mt < 2; ++mt) {
            const int kk = mt * 16 + c;
            const f32x4* crow = &cs4[kk * 17 + q * 4];
            const f32x4 vv[4] = { crow[0], crow[1], crow[2], crow[3] };
            #pragma unroll
            for (int jj = 0; jj < 8; ++jj) {
                const float cv = vv[jj >> 1][(jj & 1) * 2];
                const float sv = vv[jj >> 1][(jj & 1) * 2 + 1];
                // y = SF*(1 + cos(theta-theta_t));  y^16 = 2^-15*(1+cosd)^16
                const float y  = fmaf(cv, tc, fmaf(sv, ts, SF));
                const float y2 = y * y, y4 = y2 * y2, y8 = y4 * y4;
                afr[mt][jj] = f2bf(y8 * y8);
            }
        }

        f32x4 acc[2][4];
        #pragma unroll
        for (int mt = 0; mt < 2; ++mt)
            #pragma unroll
            for (int nt = 0; nt < 4; ++nt)
                acc[mt][nt] = (f32x4){0.0f, 0.0f, 0.0f, 0.0f};

        #pragma unroll
        for (int nt = 0; nt < 4; ++nt) {
            const short8 bfr = *(const short8*)&Pb[(nt * 64 + l) * 8];
            acc[0][nt] = __builtin_amdgcn_mfma_f32_16x16x32_bf16(afr[0], bfr, acc[0][nt], 0, 0, 0);
            acc[1][nt] = __builtin_amdgcn_mfma_f32_16x16x32_bf16(afr[1], bfr, acc[1][nt], 0, 0, 0);
        }

        // epilogue: ang[p] = sum_k B[k][p]*P[k][p]; P^T rows give b128 per (mt,nt)
        float ptv[4];
        #pragma unroll
        for (int nt = 0; nt < 4; ++nt) {
            float s = 0.0f;
            #pragma unroll
            for (int mt = 0; mt < 2; ++mt) {
                const f32x4 pv = Pt4[(nt * 16 + c) * 9 + mt * 4 + q];
                #pragma unroll
                for (int r = 0; r < 4; ++r)
                    s = fmaf(acc[mt][nt][r], pv[r], s);
            }
            s += __shfl_xor(s, 16, 64);
            s += __shfl_xor(s, 32, 64);
            ptv[nt] = s;
        }
        const float v = (q == 0) ? ptv[0] : (q == 1) ? ptv[1] : (q == 2) ? ptv[2] : ptv[3];
        descb[(size_t)i * FEATC + 64 + t * 64 + l] = (ushort)f2bf(v);
    }
}

// ---------------------------------------------------------------------------
// Kernel 2: MFMA MLP. 16 atoms/block (grid 626 -> 2x TLP vs 32/block),
// wave w = n-tile. Layer1: 18 K-steps straight from global descb (bf16).
// Layer2 via LDS H1 (bf16, stride 72). Layer3: tanh*W3, wave reduce,
// 1 atomic/block. OOB atoms masked. b3 term handled by prep_kernel.
// ---------------------------------------------------------------------------
__global__ __launch_bounds__(256) void mlp_kernel(
    const ushort* __restrict__ descb,
    const ushort* __restrict__ W1p, const float* __restrict__ b1,
    const ushort* __restrict__ W2p, const float* __restrict__ b2,
    const float* __restrict__ W3,
    float* __restrict__ out)
{
    __shared__ __attribute__((aligned(16))) ushort H1b[16 * 72];
    __shared__ float red[4];

    const int tid = threadIdx.x;
    const int w = tid >> 6, l = tid & 63;
    const int q = l >> 4, c = l & 15;
    const int a0 = blockIdx.x * 16;

    f32x4 acc = (f32x4){0.0f, 0.0f, 0.0f, 0.0f};

    #pragma unroll 6
    for (int ks = 0; ks < 18; ++ks) {
        const short8 b   = *(const short8*)&W1p[((ks * 4 + w) * 64 + l) * 8];
        const short8 afr = *(const short8*)&descb[(size_t)(a0 + c) * FEATC + ks * 32 + q * 8];
        acc = __builtin_amdgcn_mfma_f32_16x16x32_bf16(afr, b, acc, 0, 0, 0);
    }

    const float b1v = b1[w * 16 + c];
    #pragma unroll
    for (int r = 0; r < 4; ++r)
        H1b[(q * 4 + r) * 72 + w * 16 + c] = (ushort)f2bf(tanhf(acc[r] + b1v));
    __syncthreads();

    f32x4 acc2 = (f32x4){0.0f, 0.0f, 0.0f, 0.0f};
    #pragma unroll
    for (int ks = 0; ks < 2; ++ks) {
        const short8 b   = *(const short8*)&W2p[((ks * 4 + w) * 64 + l) * 8];
        const short8 afr = *(const short8*)&H1b[c * 72 + ks * 32 + q * 8];
        acc2 = __builtin_amdgcn_mfma_f32_16x16x32_bf16(afr, b, acc2, 0, 0, 0);
    }

    const float b2v = b2[w * 16 + c];
    const float w3v = W3[w * 16 + c];
    float s = 0.0f;
    #pragma unroll
    for (int r = 0; r < 4; ++r) {
        const int a = a0 + q * 4 + r;
        if (a < NATC) s += tanhf(acc2[r] + b2v) * w3v;
    }
    #pragma unroll
    for (int off = 1; off <= 32; off <<= 1)
        s += __shfl_xor(s, off, 64);
    if (l == 0) red[w] = s;
    __syncthreads();
    if (tid == 0)
        atomicAdd(out, red[0] + red[1] + red[2] + red[3]);
}

extern "C" void kernel_launch(void* const* d_in, const int* in_sizes, int n_in,
                              void* d_out, int out_size, void* d_ws, size_t ws_size,
                              hipStream_t stream)
{
    const float* pos   = (const float*)d_in[0];
    const float* spe   = (const float*)d_in[1];
    const float* theta = (const float*)d_in[2];
    const float* kn    = (const float*)d_in[3];
    const float* W1    = (const float*)d_in[4];
    const float* b1    = (const float*)d_in[5];
    const float* W2    = (const float*)d_in[6];
    const float* b2    = (const float*)d_in[7];
    const float* W3    = (const float*)d_in[8];
    const float* b3    = (const float*)d_in[9];
    const int*   nidx  = (const int*)d_in[10];
    float* out = (float*)d_out;

    // workspace layout (bytes): descb [NATP*576 u16] | W1p [36864 u16] | W2p [4096 u16]
    ushort* descb = (ushort*)d_ws;
    ushort* W1p   = (ushort*)((char*)d_ws + (size_t)NATP * FEATC * 2);   // 11,538,432
    ushort* W2p   = W1p + 4608 * 8;

    prep_kernel<<<20, 256, 0, stream>>>(W1, W2, b3, W1p, W2p, out);
    desc_kernel<<<NATC, 256, 0, stream>>>(pos, spe, theta, kn, nidx, descb);
    mlp_kernel<<<(NATC + 15) / 16, 256, 0, stream>>>(descb, W1p, b1, W2p, b2, W3, out);
}

// Round 2
// 132.286 us; speedup vs baseline: 1.1668x; 1.0156x over previous
//
#include <hip/hip_runtime.h>
#include <hip/hip_bf16.h>

#define NATC 10000
#define NATP 10016          // padded atom count for MFMA m-tiles
#define NNC 32
#define RSNC 16
#define THETANC 8
#define NEMBC 4
#define FEATC 576

typedef __attribute__((ext_vector_type(8))) short short8;  // 8 bf16 (4 VGPRs)
typedef __attribute__((ext_vector_type(4))) float f32x4;
typedef __attribute__((ext_vector_type(2))) float f32x2;

static __device__ __forceinline__ short f2bf(float x) {
    union { __hip_bfloat16 h; short s; } u;
    u.h = __float2bfloat16(x);
    return u.s;
}

// ---- packed fp32 VALU (VOP3P, gfx90a+) -----------------------------------
static __device__ __forceinline__ f32x2 pk_fma(f32x2 a, f32x2 b, f32x2 c) {
    f32x2 d;
    asm("v_pk_fma_f32 %0, %1, %2, %3" : "=v"(d) : "v"(a), "v"(b), "v"(c));
    return d;
}
static __device__ __forceinline__ f32x2 pk_mul(f32x2 a, f32x2 b) {
    f32x2 d;
    asm("v_pk_mul_f32 %0, %1, %2" : "=v"(d) : "v"(a), "v"(b));
    return d;
}
static __device__ __forceinline__ int cvt_pk_bf16(float lo, float hi) {
    int r;
    asm("v_cvt_pk_bf16_f32 %0, %1, %2" : "=v"(r) : "v"(lo), "v"(hi));
    return r;
}

// y = SF + cv*tc + sv*ts per element; returns packed bf16 of y^16
static __device__ __forceinline__ int pow16_pair(f32x2 cv, f32x2 sv,
                                                 f32x2 tcv, f32x2 tsv, f32x2 sfv) {
    f32x2 y = pk_fma(cv, tcv, pk_fma(sv, tsv, sfv));
    y = pk_mul(y, y);   // ^2
    y = pk_mul(y, y);   // ^4
    y = pk_mul(y, y);   // ^8
    y = pk_mul(y, y);   // ^16
    return cvt_pk_bf16(y[0], y[1]);
}

// ---------------------------------------------------------------------------
// desc_kernel: one block per atom (blocks 0..NATC-1); blocks >= NATC run the
// former prep_kernel (W1/W2 bf16 B-frag pack + out = NATC*b3).
//
// Layouts (all bank-audited conflict-free or 2-way):
//   Pt   [p][k]  stride 36 f32 : P^T; b128 reads for B-frags/epilogue/radial
//   cosP [kk][j] stride 36 f32 : cos(angle) plane; b128 A-operand reads
//   sinP [kk][j] stride 36 f32
// A-frag pow-16 chain + epilogue dots run on packed fp32 (v_pk_*).
// B-frags built in registers from Pt via v_cvt_pk_bf16_f32 (no LDS staging).
// Bessel basis via Chebyshev recurrence (2 trig calls/bond instead of 16).
// LDS = 9216+4608+4608+64+384+640+2176 = 21696 B.
// ---------------------------------------------------------------------------
__global__ __launch_bounds__(256, 5) void desc_kernel(
    const float* __restrict__ pos,
    const float* __restrict__ spe,
    const float* __restrict__ theta_s,
    const float* __restrict__ kn_rad,
    const int* __restrict__ nidx,
    ushort* __restrict__ descb,
    const float* __restrict__ W1, const float* __restrict__ W2,
    const float* __restrict__ b3,
    ushort* __restrict__ W1p, ushort* __restrict__ W2p,
    float* __restrict__ out)
{
    constexpr float RC = 5.0f;
    constexpr float PI_F = 3.14159265358979323846f;
    constexpr float SF = 0.52213689121f;   // 2^(-15/16); SF^16 = 2^(1-16)

    const int tid = threadIdx.x;

    // ---- prep tail blocks (former prep_kernel) ----
    if (blockIdx.x >= NATC) {
        const int gid = (blockIdx.x - NATC) * 256 + tid;   // 0..5119
        if (gid == 0) out[0] = (float)NATC * b3[0];
        if (gid < 4608) {                                  // W1: 18 ks * 4 nt * 64 l
            const int l = gid & 63, ntks = gid >> 6;
            const int nt = ntks & 3, ks = ntks >> 2;
            const int qq = l >> 4, cc = l & 15;
            ushort pk[8];
            #pragma unroll
            for (int jj = 0; jj < 8; ++jj)
                pk[jj] = (ushort)f2bf(W1[(ks * 32 + qq * 8 + jj) * 64 + nt * 16 + cc]);
            #pragma unroll
            for (int jj = 0; jj < 8; ++jj) W1p[gid * 8 + jj] = pk[jj];
        } else {                                           // W2: 2 ks * 4 nt * 64 l
            const int g = gid - 4608;
            const int l = g & 63, ntks = g >> 6;
            const int nt = ntks & 3, ks = ntks >> 2;
            const int qq = l >> 4, cc = l & 15;
            ushort pk[8];
            #pragma unroll
            for (int jj = 0; jj < 8; ++jj)
                pk[jj] = (ushort)f2bf(W2[(ks * 32 + qq * 8 + jj) * 64 + nt * 16 + cc]);
            #pragma unroll
            for (int jj = 0; jj < 8; ++jj) W2p[g * 8 + jj] = pk[jj];
        }
        return;
    }

    __shared__ __attribute__((aligned(16))) float Pt[64 * 36];    // P^T, pad 36
    __shared__ __attribute__((aligned(16))) float cosP[32 * 36];
    __shared__ __attribute__((aligned(16))) float sinP[32 * 36];
    __shared__ float thc[16];            // {SF*cos(th_t), SF*sin(th_t)} x 8
    __shared__ float ux[32], uy[32], uz[32];
    __shared__ __attribute__((aligned(16))) float ses[32 * 5];
    __shared__ __attribute__((aligned(16))) float bfs[32 * 17];

    const int i = blockIdx.x;

    // --- phase 0: bond geometry + bessel recurrence (wave0) + theta trig ---
    if (tid < NNC) {
        const int j = tid;
        const int n = nidx[i * NNC + j];
        const float pix = pos[i * 3 + 0], piy = pos[i * 3 + 1], piz = pos[i * 3 + 2];
        const float dx = pos[n * 3 + 0] - pix;
        const float dy = pos[n * 3 + 1] - piy;
        const float dz = pos[n * 3 + 2] - piz;
        const float r = sqrtf(dx * dx + dy * dy + dz * dz) + 1e-8f;
        const float inv = 1.0f / r;
        ux[j] = dx * inv; uy[j] = dy * inv; uz[j] = dz * inv;
        const float fc = (r < RC) ? 0.5f * (cosf(PI_F * r * (1.0f / RC)) + 1.0f) : 0.0f;
        const float rb = sqrtf(2.0f / RC) * inv * fc;
        const float x  = (PI_F / RC) * kn_rad[0] * r;
        // sin(kx) Chebyshev recurrence: s_k = 2cos(x) s_{k-1} - s_{k-2}
        float skm1 = sinf(x), skm2 = 0.0f;
        const float c2x = 2.0f * cosf(x);
        bfs[j * 17 + 0] = rb * skm1;
        #pragma unroll
        for (int k = 2; k <= 16; ++k) {
            const float sk = fmaf(c2x, skm1, -skm2);
            bfs[j * 17 + (k - 1)] = rb * sk;
            skm2 = skm1; skm1 = sk;
        }
        #pragma unroll
        for (int m = 0; m < NEMBC; ++m)
            ses[j * 5 + m] = spe[n * NEMBC + m] * spe[i * NEMBC + m];
    } else if (tid >= 64 && tid < 72) {
        const int t = tid - 64;
        const float th = theta_s[t];
        thc[2 * t]     = SF * cosf(th);
        thc[2 * t + 1] = SF * sinf(th);
    }
    __syncthreads();

    // --- phase 2: P^T (stride 36) + cos/sin planes (stride 36) ---
    #pragma unroll
    for (int k = 0; k < 8; ++k) {
        const int e = tid + k * 256;
        const int j = e & 31, p = e >> 5;           // j per-lane: free banks
        Pt[p * 36 + j] = bfs[j * 17 + (p >> 2)] * ses[j * 5 + (p & 3)];
    }
    #pragma unroll
    for (int k = 0; k < 4; ++k) {
        const int e = tid + k * 256;
        const int j = e & 31, kk = e >> 5;          // symmetric: c(j,kk)=c(kk,j)
        float cv = ux[j] * ux[kk] + uy[j] * uy[kk] + uz[j] * uz[kk];
        cv = fminf(fmaxf(cv, -1.0f + 1e-6f), 1.0f - 1e-6f);
        cosP[kk * 36 + j] = cv;
        sinP[kk * 36 + j] = sqrtf(fmaxf(1.0f - cv * cv, 0.0f));
    }
    __syncthreads();

    // --- phase 3: radial descriptor (wave 0, 64 lanes) ---
    if (tid < 64) {
        const f32x4* pr = (const f32x4*)&Pt[tid * 36];
        float s = 0.0f;
        #pragma unroll
        for (int kb = 0; kb < 8; ++kb) {
            const f32x4 v = pr[kb];
            s += v[0]; s += v[1]; s += v[2]; s += v[3];
        }
        descb[(size_t)i * FEATC + tid] = (ushort)f2bf(s);
    }

    // --- phase 4: MFMA contraction per theta ---
    const int w = tid >> 6, l = tid & 63;
    const int q = l >> 4, c = l & 15;

    // B-fragments (bf16) straight from Pt rows, hoisted (theta-independent)
    short8 pbr[4];
    #pragma unroll
    for (int nt = 0; nt < 4; ++nt) {
        const f32x4* prow = (const f32x4*)&Pt[(nt * 16 + c) * 36 + q * 8];
        const f32x4 p0 = prow[0], p1 = prow[1];
        union { short8 s8; int i4[4]; } u;
        u.i4[0] = cvt_pk_bf16(p0[0], p0[1]);
        u.i4[1] = cvt_pk_bf16(p0[2], p0[3]);
        u.i4[2] = cvt_pk_bf16(p1[0], p1[1]);
        u.i4[3] = cvt_pk_bf16(p1[2], p1[3]);
        pbr[nt] = u.s8;
    }

    #pragma unroll
    for (int tt = 0; tt < 2; ++tt) {
        const int t = w + tt * 4;
        const float tc = thc[2 * t], ts = thc[2 * t + 1];
        const f32x2 tcv = {tc, tc}, tsv = {ts, ts}, sfv = {SF, SF};

        // A-fragments: packed pow-16 chain from cos/sin planes
        short8 afr[2];
        #pragma unroll
        for (int mt = 0; mt < 2; ++mt) {
            const int kk = mt * 16 + c;
            const f32x4* cr = (const f32x4*)&cosP[kk * 36 + q * 8];
            const f32x4* sr = (const f32x4*)&sinP[kk * 36 + q * 8];
            const f32x4 c0 = cr[0], c1 = cr[1];
            const f32x4 s0 = sr[0], s1 = sr[1];
            union { short8 s8; int i4[4]; } u;
            u.i4[0] = pow16_pair((f32x2){c0[0], c0[1]}, (f32x2){s0[0], s0[1]}, tcv, tsv, sfv);
            u.i4[1] = pow16_pair((f32x2){c0[2], c0[3]}, (f32x2){s0[2], s0[3]}, tcv, tsv, sfv);
            u.i4[2] = pow16_pair((f32x2){c1[0], c1[1]}, (f32x2){s1[0], s1[1]}, tcv, tsv, sfv);
            u.i4[3] = pow16_pair((f32x2){c1[2], c1[3]}, (f32x2){s1[2], s1[3]}, tcv, tsv, sfv);
            afr[mt] = u.s8;
        }

        f32x4 acc[2][4];
        #pragma unroll
        for (int mt = 0; mt < 2; ++mt)
            #pragma unroll
            for (int nt = 0; nt < 4; ++nt)
                acc[mt][nt] = (f32x4){0.0f, 0.0f, 0.0f, 0.0f};

        #pragma unroll
        for (int nt = 0; nt < 4; ++nt) {
            acc[0][nt] = __builtin_amdgcn_mfma_f32_16x16x32_bf16(afr[0], pbr[nt], acc[0][nt], 0, 0, 0);
            acc[1][nt] = __builtin_amdgcn_mfma_f32_16x16x32_bf16(afr[1], pbr[nt], acc[1][nt], 0, 0, 0);
        }

        // epilogue: ang[p] = sum_k B[k][p]*P[k][p] (packed dot + q-reduce)
        float ptv[4];
        #pragma unroll
        for (int nt = 0; nt < 4; ++nt) {
            f32x2 s2 = {0.0f, 0.0f};
            #pragma unroll
            for (int mt = 0; mt < 2; ++mt) {
                const f32x4 pv = *(const f32x4*)&Pt[(nt * 16 + c) * 36 + mt * 16 + q * 4];
                const f32x4 av = acc[mt][nt];
                s2 = pk_fma((f32x2){av[0], av[1]}, (f32x2){pv[0], pv[1]}, s2);
                s2 = pk_fma((f32x2){av[2], av[3]}, (f32x2){pv[2], pv[3]}, s2);
            }
            float s = s2[0] + s2[1];
            s += __shfl_xor(s, 16, 64);
            s += __shfl_xor(s, 32, 64);
            ptv[nt] = s;
        }
        const float v = (q == 0) ? ptv[0] : (q == 1) ? ptv[1] : (q == 2) ? ptv[2] : ptv[3];
        descb[(size_t)i * FEATC + 64 + t * 64 + l] = (ushort)f2bf(v);
    }
}

// ---------------------------------------------------------------------------
// mlp_kernel: 16 atoms/block (grid 626), wave w = n-tile.
// Layer1: 18 K-steps straight from global descb (bf16). Layer2 via LDS H1.
// Layer3: tanh*W3, wave reduce, 1 atomic/block. b3 handled in desc prep tail.
// ---------------------------------------------------------------------------
__global__ __launch_bounds__(256) void mlp_kernel(
    const ushort* __restrict__ descb,
    const ushort* __restrict__ W1p, const float* __restrict__ b1,
    const ushort* __restrict__ W2p, const float* __restrict__ b2,
    const float* __restrict__ W3,
    float* __restrict__ out)
{
    __shared__ __attribute__((aligned(16))) ushort H1b[16 * 72];
    __shared__ float red[4];

    const int tid = threadIdx.x;
    const int w = tid >> 6, l = tid & 63;
    const int q = l >> 4, c = l & 15;
    const int a0 = blockIdx.x * 16;

    f32x4 acc = (f32x4){0.0f, 0.0f, 0.0f, 0.0f};

    #pragma unroll 6
    for (int ks = 0; ks < 18; ++ks) {
        const short8 b   = *(const short8*)&W1p[((ks * 4 + w) * 64 + l) * 8];
        const short8 afr = *(const short8*)&descb[(size_t)(a0 + c) * FEATC + ks * 32 + q * 8];
        acc = __builtin_amdgcn_mfma_f32_16x16x32_bf16(afr, b, acc, 0, 0, 0);
    }

    const float b1v = b1[w * 16 + c];
    #pragma unroll
    for (int r = 0; r < 4; ++r)
        H1b[(q * 4 + r) * 72 + w * 16 + c] = (ushort)f2bf(tanhf(acc[r] + b1v));
    __syncthreads();

    f32x4 acc2 = (f32x4){0.0f, 0.0f, 0.0f, 0.0f};
    #pragma unroll
    for (int ks = 0; ks < 2; ++ks) {
        const short8 b   = *(const short8*)&W2p[((ks * 4 + w) * 64 + l) * 8];
        const short8 afr = *(const short8*)&H1b[c * 72 + ks * 32 + q * 8];
        acc2 = __builtin_amdgcn_mfma_f32_16x16x32_bf16(afr, b, acc2, 0, 0, 0);
    }

    const float b2v = b2[w * 16 + c];
    const float w3v = W3[w * 16 + c];
    float s = 0.0f;
    #pragma unroll
    for (int r = 0; r < 4; ++r) {
        const int a = a0 + q * 4 + r;
        if (a < NATC) s += tanhf(acc2[r] + b2v) * w3v;
    }
    #pragma unroll
    for (int off = 1; off <= 32; off <<= 1)
        s += __shfl_xor(s, off, 64);
    if (l == 0) red[w] = s;
    __syncthreads();
    if (tid == 0)
        atomicAdd(out, red[0] + red[1] + red[2] + red[3]);
}

extern "C" void kernel_launch(void* const* d_in, const int* in_sizes, int n_in,
                              void* d_out, int out_size, void* d_ws, size_t ws_size,
                              hipStream_t stream)
{
    const float* pos   = (const float*)d_in[0];
    const float* spe   = (const float*)d_in[1];
    const float* theta = (const float*)d_in[2];
    const float* kn    = (const float*)d_in[3];
    const float* W1    = (const float*)d_in[4];
    const float* b1    = (const float*)d_in[5];
    const float* W2    = (const float*)d_in[6];
    const float* b2    = (const float*)d_in[7];
    const float* W3    = (const float*)d_in[8];
    const float* b3    = (const float*)d_in[9];
    const int*   nidx  = (const int*)d_in[10];
    float* out = (float*)d_out;

    // workspace layout (bytes): descb [NATP*576 u16] | W1p [36864 u16] | W2p [4096 u16]
    ushort* descb = (ushort*)d_ws;
    ushort* W1p   = (ushort*)((char*)d_ws + (size_t)NATP * FEATC * 2);   // 11,538,432
    ushort* W2p   = W1p + 4608 * 8;

    desc_kernel<<<NATC + 20, 256, 0, stream>>>(pos, spe, theta, kn, nidx, descb,
                                               W1, W2, b3, W1p, W2p, out);
    mlp_kernel<<<(NATC + 15) / 16, 256, 0, stream>>>(descb, W1p, b1, W2p, b2, W3, out);
}